// Round 18
// baseline (548.284 us; speedup 1.0000x reference)
//
#include <hip/hip_runtime.h>
#include <hip/hip_bf16.h>
#include <math.h>

// Problem constants (match reference)
#define BB   1024
#define MM   16
#define KK   32
#define LL   50
#define EE   64
#define NACT 100000

typedef __attribute__((ext_vector_type(8))) short short8;
typedef float v4f __attribute__((ext_vector_type(4)));

__device__ __forceinline__ float rcpf(float x) { return __builtin_amdgcn_rcpf(x); }
// native 2^x (v_exp_f32 IS exp2)
__device__ __forceinline__ float exp2_fast(float x) {
    float r;
    asm("v_exp_f32 %0, %1" : "=v"(r) : "v"(x));
    return r;
}

// packed f32x2 -> bf16x2 (lo->low16, hi->high16), RNE
__device__ __forceinline__ unsigned cvt_pk_bf16(float lo, float hi) {
    unsigned r;
    asm("v_cvt_pk_bf16_f32 %0, %1, %2" : "=v"(r) : "v"(lo), "v"(hi));
    return r;
}

// Block-wide barrier that does NOT drain vmcnt: LDS writes are made visible
// (lgkmcnt(0)) but global prefetch loads stay in flight across the barrier.
__device__ __forceinline__ void block_sync_lds() {
    __builtin_amdgcn_sched_barrier(0);
    asm volatile("s_waitcnt lgkmcnt(0)" ::: "memory");
    __builtin_amdgcn_s_barrier();
    __builtin_amdgcn_sched_barrier(0);
}

// ---------------------------------------------------------------------------
// Pre-pass: act_table f32 -> bf16 (row-major, same layout). 8 floats/thread.
// ---------------------------------------------------------------------------
__global__ __launch_bounds__(256)
void cvt_table(const float* __restrict__ src, unsigned* __restrict__ dst)
{
    const int i = blockIdx.x * 256 + threadIdx.x;          // unit = 8 floats
    if (i < (NACT * EE) / 8) {
        const float4* s = reinterpret_cast<const float4*>(src) + (size_t)i * 2;
        float4 a = s[0], b = s[1];
        uint4 o;
        o.x = cvt_pk_bf16(a.x, a.y);
        o.y = cvt_pk_bf16(a.z, a.w);
        o.z = cvt_pk_bf16(b.x, b.y);
        o.w = cvt_pk_bf16(b.z, b.w);
        reinterpret_cast<uint4*>(dst)[i] = o;
    }
}

// ---------------------------------------------------------------------------
// FULLY-FUSED kernel, r17 loop body at DOUBLE occupancy:
// 256 blocks x 512 threads. Waves 0-3 = chain-group 0 (seqs 0-31, its own
// 8 KB sH region); waves 4-7 = chain-group 1 (seqs 32-63). Per-wave work is
// identical to r17 (dual-chain + exp2 fold + setprio + prescaled-c + x-GEMM
// pipeline + fused GCN gather); the block now provides 16 waves/CU =
// 4 waves/SIMD (vs 2), filling the recurrence-latency bubbles that dominate
// (r17: VALUBusy 44%, 55% idle). Barrier spans 8 identical-shape waves.
// Epilogue handles 4 batches/block. LDS ~66 KB -> exactly 2 blocks/CU.
// ---------------------------------------------------------------------------
__global__ __launch_bounds__(512, 4)
void lstm_fused(const int* __restrict__ act_seqs, const unsigned short* __restrict__ act_bf,
                const int* __restrict__ members, const int* __restrict__ neighbors,
                const float* __restrict__ user_table,
                const float* __restrict__ W_ih, const float* __restrict__ W_hh,
                const float* __restrict__ b_ih, const float* __restrict__ b_hh,
                const int* __restrict__ act_inputs, const float* __restrict__ act_table,
                const float* __restrict__ gcn_W, const float* __restrict__ gcn_b,
                const float* __restrict__ pna_W1, const float* __restrict__ pna_b1,
                const float* __restrict__ pna_W2, const float* __restrict__ pna_b2,
                const float* __restrict__ pna_W3, const float* __restrict__ pna_b3,
                const float* __restrict__ pred_W1, const float* __restrict__ pred_b1,
                const float* __restrict__ pred_W2, const float* __restrict__ pred_b2,
                float* __restrict__ out)
{
    // --- loop-phase LDS
    __shared__ __align__(16) short sH[8][1024];   // 2 groups x (dbuf x 2 chains), 16 KB
    __shared__ int sIdx[64 * LL];                 // 12.8 KB
    __shared__ int sNbr[64 * 33];                 // 8.4 KB
    // --- epilogue LDS
    __shared__ float sFus[64][66];                // padded (16.9 KB)
    __shared__ float sF[4][256];                  // PNA feats
    __shared__ float sP[4][2][64];                // k-split partials
    __shared__ float sP7[4][8][8];                // predict partials
    __shared__ float sH1[4][64];
    __shared__ float sH2[4][64];
    __shared__ float sGrp[4][64];
    __shared__ float sActe[4][64];
    __shared__ float sHH[4][8];

    const int t    = threadIdx.x;
    const int blk  = blockIdx.x;
    const int lane = t & 63;
    const int w    = t >> 6;        // wave id 0..7
    const int g2   = w >> 2;        // chain-group 0/1
    const int we   = w & 3;         // e-block within group (0..3)
    const int lr   = lane & 15;     // A row (seq) / B,D col selector
    const int lb   = lane >> 4;     // k-block / D row-block selector

    // --- this block's indices (contiguous 3200 ints, coalesced)
    for (int i = t; i < 64 * LL; i += 512) sIdx[i] = act_seqs[blk * (64 * LL) + i];
    // --- gather row ids: pair p (= global b*16+m = blk*64+p), j=0 member, 1..32 nbrs
    for (int i = t; i < 64 * 33; i += 512) {
        const int p = i / 33, j = i - p * 33;
        const int base = blk * 64 + p;
        sNbr[i] = (j == 0) ? members[base] : neighbors[base * KK + j - 1];
    }
    // --- stage act_e for the 4 batches
    if (t < 256) {
        const int q = t >> 6, e = t & 63;
        sActe[q][e] = act_table[(size_t)act_inputs[blk * 4 + q] * EE + e];
    }

    // per-gate exp2 fold scales (i,f,o: -log2e; g: +2*log2e)
    const float L2E = 1.44269504088896f;
    float gscale[4];
    gscale[0] = -L2E; gscale[1] = -L2E; gscale[2] = 2.0f * L2E; gscale[3] = -L2E;

    // --- weights -> register B-frags, SCALED. gates = in @ W^T => B[k][j]=W[j][k].
    short8 Bf[2][4][2];   // [mat(ih,hh)][gate][ks]
    #pragma unroll
    for (int mat = 0; mat < 2; ++mat) {
        const float* W = mat ? W_hh : W_ih;
        #pragma unroll
        for (int g = 0; g < 4; ++g) {
            const int j = g * 64 + we * 16 + lr;
            const float sc = gscale[g];
            #pragma unroll
            for (int ks = 0; ks < 2; ++ks) {
                const float4* p = reinterpret_cast<const float4*>(&W[(size_t)j * 64 + ks * 32 + lb * 8]);
                float4 v0 = p[0], v1 = p[1];
                uint4 o;
                o.x = cvt_pk_bf16(sc * v0.x, sc * v0.y);
                o.y = cvt_pk_bf16(sc * v0.z, sc * v0.w);
                o.z = cvt_pk_bf16(sc * v1.x, sc * v1.y);
                o.w = cvt_pk_bf16(sc * v1.z, sc * v1.w);
                Bf[mat][g][ks] = __builtin_bit_cast(short8, o);
            }
        }
    }
    // --- gcn_W -> register B-frags (epilogue MFMA), unscaled bf16 RNE
    short8 Bg[2];
    #pragma unroll
    for (int ks = 0; ks < 2; ++ks) {
        const int j = we * 16 + lr;
        const float4* p = reinterpret_cast<const float4*>(&gcn_W[(size_t)j * 64 + ks * 32 + lb * 8]);
        float4 v0 = p[0], v1 = p[1];
        uint4 o;
        o.x = cvt_pk_bf16(v0.x, v0.y);
        o.y = cvt_pk_bf16(v0.z, v0.w);
        o.z = cvt_pk_bf16(v1.x, v1.y);
        o.w = cvt_pk_bf16(v1.z, v1.w);
        Bg[ks] = __builtin_bit_cast(short8, o);
    }
    const float gb = gcn_b[we * 16 + lr];

    float bias[4];
    #pragma unroll
    for (int g = 0; g < 4; ++g) {
        const int j = g * 64 + we * 16 + lr;
        bias[g] = gscale[g] * (b_ih[j] + b_hh[j]);
    }

    // cell state kept pre-scaled: c~ = 2*L2E*c
    float hA[4], cA[4], hB[4], cB[4];
    #pragma unroll
    for (int r = 0; r < 4; ++r) { hA[r] = 0.0f; cA[r] = 0.0f; hB[r] = 0.0f; cB[r] = 0.0f; }

    // zero all sH (16 KB = 1024 x uint4; 512 threads x 2)
    reinterpret_cast<uint4*>(sH)[t]       = make_uint4(0u, 0u, 0u, 0u);
    reinterpret_cast<uint4*>(sH)[t + 512] = make_uint4(0u, 0u, 0u, 0u);
    __syncthreads();   // sIdx + sNbr + sActe + sH visible (once)

    // --- gather lane mapping: pair p = t>>3 owns row blk*64+p; chunk ec = t&7
    const int gpair = t >> 3;     // 0..63
    const int gec   = t & 7;
    const float* gut = user_table + (size_t)gec * 8;
    float gacc[8];
    #pragma unroll
    for (int q = 0; q < 8; ++q) gacc[q] = 0.0f;
    // pre-issue gather row 0 (BEFORE x pre-loads: older in vmcnt FIFO)
    float4 gld0, gld1;
    {
        const int gi = sNbr[gpair * 33 + 0];
        const float4* gp = reinterpret_cast<const float4*>(gut + (size_t)gi * EE);
        gld0 = gp[0]; gld1 = gp[1];
    }

    // --- x gather: lane's frag = bytes [id*128 + lb*16] and +64.
    const char* tbl8 = reinterpret_cast<const char*>(act_bf) + lb * 16;
    const int ibA = (g2 * 32 + lr) * LL;        // chain A: seq g2*32 + lr
    const int ibB = (g2 * 32 + 16 + lr) * LL;   // chain B: seq g2*32 + 16 + lr

    // prologue: load x_0, compute xacc for step 0; load x_1 -> px; idx -> x_2
    int idA = sIdx[ibA + 0], idB = sIdx[ibB + 0];
    short8 c0A0 = *reinterpret_cast<const short8*>(tbl8 + (size_t)idA * 128);
    short8 c0A1 = *reinterpret_cast<const short8*>(tbl8 + (size_t)idA * 128 + 64);
    short8 c0B0 = *reinterpret_cast<const short8*>(tbl8 + (size_t)idB * 128);
    short8 c0B1 = *reinterpret_cast<const short8*>(tbl8 + (size_t)idB * 128 + 64);
    idA = sIdx[ibA + 1]; idB = sIdx[ibB + 1];
    short8 pxA0 = *reinterpret_cast<const short8*>(tbl8 + (size_t)idA * 128);
    short8 pxA1 = *reinterpret_cast<const short8*>(tbl8 + (size_t)idA * 128 + 64);
    short8 pxB0 = *reinterpret_cast<const short8*>(tbl8 + (size_t)idB * 128);
    short8 pxB1 = *reinterpret_cast<const short8*>(tbl8 + (size_t)idB * 128 + 64);
    idA = sIdx[ibA + 2]; idB = sIdx[ibB + 2];

    v4f xaccA[4], xaccB[4];
    #pragma unroll
    for (int g = 0; g < 4; ++g) {
        v4f a; a[0] = bias[g]; a[1] = bias[g]; a[2] = bias[g]; a[3] = bias[g];
        a = __builtin_amdgcn_mfma_f32_16x16x32_bf16(c0A0, Bf[0][g][0], a, 0, 0, 0);
        xaccA[g] = __builtin_amdgcn_mfma_f32_16x16x32_bf16(c0A1, Bf[0][g][1], a, 0, 0, 0);
        v4f b; b[0] = bias[g]; b[1] = bias[g]; b[2] = bias[g]; b[3] = bias[g];
        b = __builtin_amdgcn_mfma_f32_16x16x32_bf16(c0B0, Bf[0][g][0], b, 0, 0, 0);
        xaccB[g] = __builtin_amdgcn_mfma_f32_16x16x32_bf16(c0B1, Bf[0][g][1], b, 0, 0, 0);
    }

    // LDS byte offsets (loop-invariant); group base = g2*8192
    const int offA0 = lr * 128 + ((lb ^ (lr & 7)) << 4);
    const int offA1 = lr * 128 + (((lb + 4) ^ (lr & 7)) << 4);
    int hw_off[4];
    #pragma unroll
    for (int r = 0; r < 4; ++r) {
        const int s = lb * 4 + r, e = we * 16 + lr;
        hw_off[r] = s * 128 + ((((e >> 3) ^ (s & 7)) << 4)) + (e & 7) * 2;
    }
    char* const sHb = reinterpret_cast<char*>(sH);
    char* const sHg = sHb + g2 * 8192;   // this group's loop region

    const float TL2 = 2.0f * L2E;   // 2*log2e

    #pragma unroll 2
    for (int step = 0; step < LL; ++step) {
        const int cb  = (step & 1) << 12;   // current buf base within group
        const int nb_ = cb ^ 4096;          // next buf base

        // 0. fused GCN gather (low prio): accumulate row `step`, issue row step+1
        if (step < 33) {
            gacc[0] += gld0.x; gacc[1] += gld0.y; gacc[2] += gld0.z; gacc[3] += gld0.w;
            gacc[4] += gld1.x; gacc[5] += gld1.y; gacc[6] += gld1.z; gacc[7] += gld1.w;
            if (step < 32) {
                const int gi = sNbr[gpair * 33 + step + 1];
                const float4* gp = reinterpret_cast<const float4*>(gut + (size_t)gi * EE);
                gld0 = gp[0]; gld1 = gp[1];
            }
        }

        // 1. issue x prefetch for step+2 (stays in flight across the barrier)
        short8 nxA0 = *reinterpret_cast<const short8*>(tbl8 + (size_t)idA * 128);
        short8 nxA1 = *reinterpret_cast<const short8*>(tbl8 + (size_t)idA * 128 + 64);
        short8 nxB0 = *reinterpret_cast<const short8*>(tbl8 + (size_t)idB * 128);
        short8 nxB1 = *reinterpret_cast<const short8*>(tbl8 + (size_t)idB * 128 + 64);
        {
            const int s2 = (step + 3 < LL) ? (step + 3) : (LL - 1);
            idA = sIdx[ibA + s2]; idB = sIdx[ibB + s2];
        }

        // ---- recurrence-critical section: prefer this wave on the CU ----
        __builtin_amdgcn_s_setprio(1);

        // 2. read h A-frags for both chains (swizzled, conflict-free)
        short8 ahA0 = *reinterpret_cast<const short8*>(sHg + cb + offA0);
        short8 ahA1 = *reinterpret_cast<const short8*>(sHg + cb + offA1);
        short8 ahB0 = *reinterpret_cast<const short8*>(sHg + cb + 2048 + offA0);
        short8 ahB1 = *reinterpret_cast<const short8*>(sHg + cb + 2048 + offA1);

        // 3. acc = xacc (bias + x-part, computed last step) + h @ sWhh^T
        v4f accA[4], accB[4];
        #pragma unroll
        for (int g = 0; g < 4; ++g) {
            v4f a = __builtin_amdgcn_mfma_f32_16x16x32_bf16(ahA0, Bf[1][g][0], xaccA[g], 0, 0, 0);
            accA[g] = __builtin_amdgcn_mfma_f32_16x16x32_bf16(ahA1, Bf[1][g][1], a, 0, 0, 0);
            v4f b = __builtin_amdgcn_mfma_f32_16x16x32_bf16(ahB0, Bf[1][g][0], xaccB[g], 0, 0, 0);
            accB[g] = __builtin_amdgcn_mfma_f32_16x16x32_bf16(ahB1, Bf[1][g][1], b, 0, 0, 0);
        }

        // 4. gate nonlinearities + h writes (pre-scaled c~; exp2 arg direct)
        {
            char* SH = sHg + nb_;
            #pragma unroll
            for (int r = 0; r < 4; ++r) {
                const float si = rcpf(1.0f + exp2_fast(accA[0][r]));
                const float sf = rcpf(1.0f + exp2_fast(accA[1][r]));
                const float tgs = fmaf(-2.0f * TL2, rcpf(1.0f + exp2_fast(accA[2][r])), TL2);
                const float so = rcpf(1.0f + exp2_fast(accA[3][r]));
                const float cc = fmaf(sf, cA[r], si * tgs);
                cA[r] = cc;
                hA[r] = so * fmaf(-2.0f, rcpf(1.0f + exp2_fast(cc)), 1.0f);
            }
            const unsigned a01 = cvt_pk_bf16(hA[0], hA[1]);
            const unsigned a23 = cvt_pk_bf16(hA[2], hA[3]);
            *reinterpret_cast<short*>(SH + hw_off[0]) = (short)(a01 & 0xFFFF);
            *reinterpret_cast<short*>(SH + hw_off[1]) = (short)(a01 >> 16);
            *reinterpret_cast<short*>(SH + hw_off[2]) = (short)(a23 & 0xFFFF);
            *reinterpret_cast<short*>(SH + hw_off[3]) = (short)(a23 >> 16);
            SH += 2048;
            #pragma unroll
            for (int r = 0; r < 4; ++r) {
                const float si = rcpf(1.0f + exp2_fast(accB[0][r]));
                const float sf = rcpf(1.0f + exp2_fast(accB[1][r]));
                const float tgs = fmaf(-2.0f * TL2, rcpf(1.0f + exp2_fast(accB[2][r])), TL2);
                const float so = rcpf(1.0f + exp2_fast(accB[3][r]));
                const float cc = fmaf(sf, cB[r], si * tgs);
                cB[r] = cc;
                hB[r] = so * fmaf(-2.0f, rcpf(1.0f + exp2_fast(cc)), 1.0f);
            }
            const unsigned b01 = cvt_pk_bf16(hB[0], hB[1]);
            const unsigned b23 = cvt_pk_bf16(hB[2], hB[3]);
            *reinterpret_cast<short*>(SH + hw_off[0]) = (short)(b01 & 0xFFFF);
            *reinterpret_cast<short*>(SH + hw_off[1]) = (short)(b01 >> 16);
            *reinterpret_cast<short*>(SH + hw_off[2]) = (short)(b23 & 0xFFFF);
            *reinterpret_cast<short*>(SH + hw_off[3]) = (short)(b23 >> 16);
        }

        __builtin_amdgcn_s_setprio(0);
        // ---- end critical section ----

        // 5. x-part of step+1's gates (off critical path; overlaps barrier wait)
        #pragma unroll
        for (int g = 0; g < 4; ++g) {
            v4f a; a[0] = bias[g]; a[1] = bias[g]; a[2] = bias[g]; a[3] = bias[g];
            a = __builtin_amdgcn_mfma_f32_16x16x32_bf16(pxA0, Bf[0][g][0], a, 0, 0, 0);
            xaccA[g] = __builtin_amdgcn_mfma_f32_16x16x32_bf16(pxA1, Bf[0][g][1], a, 0, 0, 0);
            v4f b; b[0] = bias[g]; b[1] = bias[g]; b[2] = bias[g]; b[3] = bias[g];
            b = __builtin_amdgcn_mfma_f32_16x16x32_bf16(pxB0, Bf[0][g][0], b, 0, 0, 0);
            xaccB[g] = __builtin_amdgcn_mfma_f32_16x16x32_bf16(pxB1, Bf[0][g][1], b, 0, 0, 0);
        }

        // 6. LDS-only barrier (x + gather loads stay in flight)
        block_sync_lds();

        // 7. roll prefetch regs
        pxA0 = nxA0; pxA1 = nxA1; pxB0 = nxB0; pxB1 = nxB1;
    }

    // ======================= FUSED POST EPILOGUE =======================
    // batches q=0..3 -> global b = blk*4 + q; local pair p = q*16 + m.

    // 1. stage agg/33 as bf16 into dead sH tiles 0..3 (same swizzle as h)
    {
        const float sc = 1.0f / 33.0f;
        uint4 pk;
        pk.x = cvt_pk_bf16(gacc[0] * sc, gacc[1] * sc);
        pk.y = cvt_pk_bf16(gacc[2] * sc, gacc[3] * sc);
        pk.z = cvt_pk_bf16(gacc[4] * sc, gacc[5] * sc);
        pk.w = cvt_pk_bf16(gacc[6] * sc, gacc[7] * sc);
        const int row = gpair & 15;
        const int off = ((gpair >> 4) << 11) + row * 128 + ((gec ^ (row & 7)) << 4);
        *reinterpret_cast<uint4*>(sHb + off) = pk;
    }
    __syncthreads();

    // 2. m_gcn = relu(agg @ gcn_W^T + b) via MFMA; fus = h + m_gcn.
    //    group g2 consumes tiles 2*g2 (chain A rows) and 2*g2+1 (chain B rows).
    {
        const char* base = sHb + g2 * 4096;
        short8 agA0 = *reinterpret_cast<const short8*>(base + offA0);
        short8 agA1 = *reinterpret_cast<const short8*>(base + offA1);
        short8 agB0 = *reinterpret_cast<const short8*>(base + 2048 + offA0);
        short8 agB1 = *reinterpret_cast<const short8*>(base + 2048 + offA1);
        v4f z4 = {0.0f, 0.0f, 0.0f, 0.0f};
        v4f gA = __builtin_amdgcn_mfma_f32_16x16x32_bf16(agA0, Bg[0], z4, 0, 0, 0);
        gA = __builtin_amdgcn_mfma_f32_16x16x32_bf16(agA1, Bg[1], gA, 0, 0, 0);
        v4f gB = __builtin_amdgcn_mfma_f32_16x16x32_bf16(agB0, Bg[0], z4, 0, 0, 0);
        gB = __builtin_amdgcn_mfma_f32_16x16x32_bf16(agB1, Bg[1], gB, 0, 0, 0);
        const int e = we * 16 + lr;
        #pragma unroll
        for (int r = 0; r < 4; ++r) {
            sFus[g2 * 32 + lb * 4 + r][e]      = hA[r] + fmaxf(gA[r] + gb, 0.0f);
            sFus[g2 * 32 + 16 + lb * 4 + r][e] = hB[r] + fmaxf(gB[r] + gb, 0.0f);
        }
    }
    __syncthreads();

    // 3. PNA reduce over M (amp = 1 exactly)
    if (t < 256) {
        const int q = t >> 6, e = t & 63;
        float mn = 0.0f, mx = -INFINITY;
        #pragma unroll
        for (int m = 0; m < MM; ++m) { float v = sFus[q * 16 + m][e]; mn += v; mx = fmaxf(mx, v); }
        mn *= (1.0f / 16.0f);
        sF[q][e] = mn; sF[q][64 + e] = mx; sF[q][128 + e] = mn; sF[q][192 + e] = mx;
    }
    __syncthreads();

    // 4. h1 = relu(feats @ pna_W1 + b1): 256->64; 4 batches x 2 k-halves x 64
    {
        const int q = t >> 7, kh = (t >> 6) & 1, j = t & 63;
        float p = 0.0f;
        const float* Wp = pna_W1 + (size_t)(kh * 128) * 64 + j;
        const float* fp = &sF[q][kh * 128];
        #pragma unroll 16
        for (int k = 0; k < 128; ++k) p = fmaf(fp[k], Wp[(size_t)k * 64], p);
        sP[q][kh][j] = p;
    }
    __syncthreads();
    if (t < 256) {
        const int q = t >> 6, j = t & 63;
        sH1[q][j] = fmaxf(pna_b1[j] + sP[q][0][j] + sP[q][1][j], 0.0f);
    }
    __syncthreads();

    // 5. h2 = relu(h1 @ pna_W2 + b2): k split 2x32
    {
        const int q = t >> 7, kh = (t >> 6) & 1, j = t & 63;
        float p = 0.0f;
        #pragma unroll
        for (int k = 0; k < 32; ++k)
            p = fmaf(sH1[q][kh * 32 + k], pna_W2[(size_t)(kh * 32 + k) * 64 + j], p);
        sP[q][kh][j] = p;
    }
    __syncthreads();
    if (t < 256) {
        const int q = t >> 6, j = t & 63;
        sH2[q][j] = fmaxf(pna_b2[j] + sP[q][0][j] + sP[q][1][j], 0.0f);
    }
    __syncthreads();

    // 6. grp = h2 @ pna_W3 + b3: k split 2x32
    {
        const int q = t >> 7, kh = (t >> 6) & 1, j = t & 63;
        float p = 0.0f;
        #pragma unroll
        for (int k = 0; k < 32; ++k)
            p = fmaf(sH2[q][kh * 32 + k], pna_W3[(size_t)(kh * 32 + k) * 64 + j], p);
        sP[q][kh][j] = p;
    }
    __syncthreads();
    if (t < 256) {
        const int q = t >> 6, j = t & 63;
        sGrp[q][j] = pna_b3[j] + sP[q][0][j] + sP[q][1][j];
    }
    __syncthreads();

    // 7. predict layer 1: 256 threads, k split 8x24; then 32-thread combine
    if (t < 256) {
        const int q = t >> 6, kg = (t >> 3) & 7, j = t & 7;
        float a = 0.0f;
        #pragma unroll
        for (int kk = 0; kk < 24; ++kk) {
            const int k = kg * 24 + kk;
            const float cv = (k < 64) ? sGrp[q][k] * sActe[q][k]
                                      : ((k < 128) ? sGrp[q][k - 64] : sActe[q][k - 128]);
            a = fmaf(cv, pred_W1[k * 8 + j], a);
        }
        sP7[q][kg][j] = a;
    }
    __syncthreads();
    if (t < 32) {
        const int q = t >> 3, j = t & 7;
        float a = pred_b1[j];
        #pragma unroll
        for (int kg = 0; kg < 8; ++kg) a += sP7[q][kg][j];
        sHH[q][j] = fmaxf(a, 0.0f);
    }
    __syncthreads();
    if (t < 4) {
        float y = pred_b2[0];
        #pragma unroll
        for (int jj = 0; jj < 8; ++jj) y = fmaf(sHH[t][jj], pred_W2[jj], y);
        out[blk * 4 + t] = 1.0f / (1.0f + expf(-y));
    }
}

extern "C" void kernel_launch(void* const* d_in, const int* in_sizes, int n_in,
                              void* d_out, int out_size, void* d_ws, size_t ws_size,
                              hipStream_t stream) {
    const int*   members    = (const int*)d_in[0];
    const int*   neighbors  = (const int*)d_in[1];
    const int*   act_inputs = (const int*)d_in[2];
    const int*   act_seqs   = (const int*)d_in[3];
    const float* act_table  = (const float*)d_in[4];
    const float* user_table = (const float*)d_in[5];
    const float* W_ih       = (const float*)d_in[6];
    const float* W_hh       = (const float*)d_in[7];
    const float* b_ih       = (const float*)d_in[8];
    const float* b_hh       = (const float*)d_in[9];
    const float* gcn_W      = (const float*)d_in[10];
    const float* gcn_b      = (const float*)d_in[11];
    const float* pna_W1     = (const float*)d_in[12];
    const float* pna_b1     = (const float*)d_in[13];
    const float* pna_W2     = (const float*)d_in[14];
    const float* pna_b2     = (const float*)d_in[15];
    const float* pna_W3     = (const float*)d_in[16];
    const float* pna_b3     = (const float*)d_in[17];
    const float* pred_W1    = (const float*)d_in[18];
    const float* pred_b1    = (const float*)d_in[19];
    const float* pred_W2    = (const float*)d_in[20];
    const float* pred_b2    = (const float*)d_in[21];

    unsigned short* act_bf = (unsigned short*)d_ws;   // 12.8 MB bf16 table

    cvt_table<<<dim3((NACT * EE / 8 + 255) / 256), dim3(256), 0, stream>>>(
        act_table, (unsigned*)act_bf);

    lstm_fused<<<dim3(256), dim3(512), 0, stream>>>(
        act_seqs, act_bf, members, neighbors, user_table,
        W_ih, W_hh, b_ih, b_hh,
        act_inputs, act_table,
        gcn_W, gcn_b, pna_W1, pna_b1, pna_W2, pna_b2, pna_W3, pna_b3,
        pred_W1, pred_b1, pred_W2, pred_b2, (float*)d_out);
}

// Round 19
// 114.157 us; speedup vs baseline: 4.8029x; 4.8029x over previous
//
#include <hip/hip_runtime.h>
#include <hip/hip_bf16.h>
#include <math.h>

// Problem constants (match reference)
#define BB   1024
#define MM   16
#define KK   32
#define LL   50
#define EE   64
#define NACT 100000

typedef __attribute__((ext_vector_type(8))) short short8;
typedef float v4f __attribute__((ext_vector_type(4)));

__device__ __forceinline__ float rcpf(float x) { return __builtin_amdgcn_rcpf(x); }
// native 2^x (v_exp_f32 IS exp2)
__device__ __forceinline__ float exp2_fast(float x) {
    float r;
    asm("v_exp_f32 %0, %1" : "=v"(r) : "v"(x));
    return r;
}

// packed f32x2 -> bf16x2 (lo->low16, hi->high16), RNE
__device__ __forceinline__ unsigned cvt_pk_bf16(float lo, float hi) {
    unsigned r;
    asm("v_cvt_pk_bf16_f32 %0, %1, %2" : "=v"(r) : "v"(lo), "v"(hi));
    return r;
}

// Block-wide barrier that does NOT drain vmcnt: LDS writes are made visible
// (lgkmcnt(0)) but global prefetch loads stay in flight across the barrier.
__device__ __forceinline__ void block_sync_lds() {
    __builtin_amdgcn_sched_barrier(0);
    asm volatile("s_waitcnt lgkmcnt(0)" ::: "memory");
    __builtin_amdgcn_s_barrier();
    __builtin_amdgcn_sched_barrier(0);
}

// ---------------------------------------------------------------------------
// Pre-pass: act_table f32 -> bf16 (row-major, same layout). 8 floats/thread.
// ---------------------------------------------------------------------------
__global__ __launch_bounds__(256)
void cvt_table(const float* __restrict__ src, unsigned* __restrict__ dst)
{
    const int i = blockIdx.x * 256 + threadIdx.x;          // unit = 8 floats
    if (i < (NACT * EE) / 8) {
        const float4* s = reinterpret_cast<const float4*>(src) + (size_t)i * 2;
        float4 a = s[0], b = s[1];
        uint4 o;
        o.x = cvt_pk_bf16(a.x, a.y);
        o.y = cvt_pk_bf16(a.z, a.w);
        o.z = cvt_pk_bf16(b.x, b.y);
        o.w = cvt_pk_bf16(b.z, b.w);
        reinterpret_cast<uint4*>(dst)[i] = o;
    }
}

// ---------------------------------------------------------------------------
// FULLY-FUSED kernel, r17 loop body at 256 blocks x 512 threads.
// r18 RETRY with the spill variable removed: __launch_bounds__(512, 2)
// (register cap 256 -- the allocator uses its natural ~116-130, and
// occupancy comes from the ACTUAL allocation: floor(512/regs) waves/SIMD).
// r18's (512,4) forced a 128-reg cap -> ~70-reg scratch spill -> 548 us.
// Waves 0-3 = chain-group 0 (seqs 0-31); waves 4-7 = group 1 (seqs 32-63);
// per-wave work identical to r17. Epilogue handles 4 batches/block.
// LDS ~66 KB -> up to 2 blocks/CU (wave-slot + LDS limited).
// ---------------------------------------------------------------------------
__global__ __launch_bounds__(512, 2)
void lstm_fused(const int* __restrict__ act_seqs, const unsigned short* __restrict__ act_bf,
                const int* __restrict__ members, const int* __restrict__ neighbors,
                const float* __restrict__ user_table,
                const float* __restrict__ W_ih, const float* __restrict__ W_hh,
                const float* __restrict__ b_ih, const float* __restrict__ b_hh,
                const int* __restrict__ act_inputs, const float* __restrict__ act_table,
                const float* __restrict__ gcn_W, const float* __restrict__ gcn_b,
                const float* __restrict__ pna_W1, const float* __restrict__ pna_b1,
                const float* __restrict__ pna_W2, const float* __restrict__ pna_b2,
                const float* __restrict__ pna_W3, const float* __restrict__ pna_b3,
                const float* __restrict__ pred_W1, const float* __restrict__ pred_b1,
                const float* __restrict__ pred_W2, const float* __restrict__ pred_b2,
                float* __restrict__ out)
{
    // --- loop-phase LDS
    __shared__ __align__(16) short sH[8][1024];   // 2 groups x (dbuf x 2 chains), 16 KB
    __shared__ int sIdx[64 * LL];                 // 12.8 KB
    __shared__ int sNbr[64 * 33];                 // 8.4 KB
    // --- epilogue LDS
    __shared__ float sFus[64][66];                // padded (16.9 KB)
    __shared__ float sF[4][256];                  // PNA feats
    __shared__ float sP[4][2][64];                // k-split partials
    __shared__ float sP7[4][8][8];                // predict partials
    __shared__ float sH1[4][64];
    __shared__ float sH2[4][64];
    __shared__ float sGrp[4][64];
    __shared__ float sActe[4][64];
    __shared__ float sHH[4][8];

    const int t    = threadIdx.x;
    const int blk  = blockIdx.x;
    const int lane = t & 63;
    const int w    = t >> 6;        // wave id 0..7
    const int g2   = w >> 2;        // chain-group 0/1
    const int we   = w & 3;         // e-block within group (0..3)
    const int lr   = lane & 15;     // A row (seq) / B,D col selector
    const int lb   = lane >> 4;     // k-block / D row-block selector

    // --- this block's indices (contiguous 3200 ints, coalesced)
    for (int i = t; i < 64 * LL; i += 512) sIdx[i] = act_seqs[blk * (64 * LL) + i];
    // --- gather row ids: pair p (= global b*16+m = blk*64+p), j=0 member, 1..32 nbrs
    for (int i = t; i < 64 * 33; i += 512) {
        const int p = i / 33, j = i - p * 33;
        const int base = blk * 64 + p;
        sNbr[i] = (j == 0) ? members[base] : neighbors[base * KK + j - 1];
    }
    // --- stage act_e for the 4 batches
    if (t < 256) {
        const int q = t >> 6, e = t & 63;
        sActe[q][e] = act_table[(size_t)act_inputs[blk * 4 + q] * EE + e];
    }

    // per-gate exp2 fold scales (i,f,o: -log2e; g: +2*log2e)
    const float L2E = 1.44269504088896f;
    float gscale[4];
    gscale[0] = -L2E; gscale[1] = -L2E; gscale[2] = 2.0f * L2E; gscale[3] = -L2E;

    // --- weights -> register B-frags, SCALED. gates = in @ W^T => B[k][j]=W[j][k].
    short8 Bf[2][4][2];   // [mat(ih,hh)][gate][ks]
    #pragma unroll
    for (int mat = 0; mat < 2; ++mat) {
        const float* W = mat ? W_hh : W_ih;
        #pragma unroll
        for (int g = 0; g < 4; ++g) {
            const int j = g * 64 + we * 16 + lr;
            const float sc = gscale[g];
            #pragma unroll
            for (int ks = 0; ks < 2; ++ks) {
                const float4* p = reinterpret_cast<const float4*>(&W[(size_t)j * 64 + ks * 32 + lb * 8]);
                float4 v0 = p[0], v1 = p[1];
                uint4 o;
                o.x = cvt_pk_bf16(sc * v0.x, sc * v0.y);
                o.y = cvt_pk_bf16(sc * v0.z, sc * v0.w);
                o.z = cvt_pk_bf16(sc * v1.x, sc * v1.y);
                o.w = cvt_pk_bf16(sc * v1.z, sc * v1.w);
                Bf[mat][g][ks] = __builtin_bit_cast(short8, o);
            }
        }
    }
    // --- gcn_W -> register B-frags (epilogue MFMA), unscaled bf16 RNE
    short8 Bg[2];
    #pragma unroll
    for (int ks = 0; ks < 2; ++ks) {
        const int j = we * 16 + lr;
        const float4* p = reinterpret_cast<const float4*>(&gcn_W[(size_t)j * 64 + ks * 32 + lb * 8]);
        float4 v0 = p[0], v1 = p[1];
        uint4 o;
        o.x = cvt_pk_bf16(v0.x, v0.y);
        o.y = cvt_pk_bf16(v0.z, v0.w);
        o.z = cvt_pk_bf16(v1.x, v1.y);
        o.w = cvt_pk_bf16(v1.z, v1.w);
        Bg[ks] = __builtin_bit_cast(short8, o);
    }
    const float gb = gcn_b[we * 16 + lr];

    float bias[4];
    #pragma unroll
    for (int g = 0; g < 4; ++g) {
        const int j = g * 64 + we * 16 + lr;
        bias[g] = gscale[g] * (b_ih[j] + b_hh[j]);
    }

    // cell state kept pre-scaled: c~ = 2*L2E*c
    float hA[4], cA[4], hB[4], cB[4];
    #pragma unroll
    for (int r = 0; r < 4; ++r) { hA[r] = 0.0f; cA[r] = 0.0f; hB[r] = 0.0f; cB[r] = 0.0f; }

    // zero all sH (16 KB = 1024 x uint4; 512 threads x 2)
    reinterpret_cast<uint4*>(sH)[t]       = make_uint4(0u, 0u, 0u, 0u);
    reinterpret_cast<uint4*>(sH)[t + 512] = make_uint4(0u, 0u, 0u, 0u);
    __syncthreads();   // sIdx + sNbr + sActe + sH visible (once)

    // --- gather lane mapping: pair p = t>>3 owns row blk*64+p; chunk ec = t&7
    const int gpair = t >> 3;     // 0..63
    const int gec   = t & 7;
    const float* gut = user_table + (size_t)gec * 8;
    float gacc[8];
    #pragma unroll
    for (int q = 0; q < 8; ++q) gacc[q] = 0.0f;
    // pre-issue gather row 0 (BEFORE x pre-loads: older in vmcnt FIFO)
    float4 gld0, gld1;
    {
        const int gi = sNbr[gpair * 33 + 0];
        const float4* gp = reinterpret_cast<const float4*>(gut + (size_t)gi * EE);
        gld0 = gp[0]; gld1 = gp[1];
    }

    // --- x gather: lane's frag = bytes [id*128 + lb*16] and +64.
    const char* tbl8 = reinterpret_cast<const char*>(act_bf) + lb * 16;
    const int ibA = (g2 * 32 + lr) * LL;        // chain A: seq g2*32 + lr
    const int ibB = (g2 * 32 + 16 + lr) * LL;   // chain B: seq g2*32 + 16 + lr

    // prologue: load x_0, compute xacc for step 0; load x_1 -> px; idx -> x_2
    int idA = sIdx[ibA + 0], idB = sIdx[ibB + 0];
    short8 c0A0 = *reinterpret_cast<const short8*>(tbl8 + (size_t)idA * 128);
    short8 c0A1 = *reinterpret_cast<const short8*>(tbl8 + (size_t)idA * 128 + 64);
    short8 c0B0 = *reinterpret_cast<const short8*>(tbl8 + (size_t)idB * 128);
    short8 c0B1 = *reinterpret_cast<const short8*>(tbl8 + (size_t)idB * 128 + 64);
    idA = sIdx[ibA + 1]; idB = sIdx[ibB + 1];
    short8 pxA0 = *reinterpret_cast<const short8*>(tbl8 + (size_t)idA * 128);
    short8 pxA1 = *reinterpret_cast<const short8*>(tbl8 + (size_t)idA * 128 + 64);
    short8 pxB0 = *reinterpret_cast<const short8*>(tbl8 + (size_t)idB * 128);
    short8 pxB1 = *reinterpret_cast<const short8*>(tbl8 + (size_t)idB * 128 + 64);
    idA = sIdx[ibA + 2]; idB = sIdx[ibB + 2];

    v4f xaccA[4], xaccB[4];
    #pragma unroll
    for (int g = 0; g < 4; ++g) {
        v4f a; a[0] = bias[g]; a[1] = bias[g]; a[2] = bias[g]; a[3] = bias[g];
        a = __builtin_amdgcn_mfma_f32_16x16x32_bf16(c0A0, Bf[0][g][0], a, 0, 0, 0);
        xaccA[g] = __builtin_amdgcn_mfma_f32_16x16x32_bf16(c0A1, Bf[0][g][1], a, 0, 0, 0);
        v4f b; b[0] = bias[g]; b[1] = bias[g]; b[2] = bias[g]; b[3] = bias[g];
        b = __builtin_amdgcn_mfma_f32_16x16x32_bf16(c0B0, Bf[0][g][0], b, 0, 0, 0);
        xaccB[g] = __builtin_amdgcn_mfma_f32_16x16x32_bf16(c0B1, Bf[0][g][1], b, 0, 0, 0);
    }

    // LDS byte offsets (loop-invariant); group base = g2*8192
    const int offA0 = lr * 128 + ((lb ^ (lr & 7)) << 4);
    const int offA1 = lr * 128 + (((lb + 4) ^ (lr & 7)) << 4);
    int hw_off[4];
    #pragma unroll
    for (int r = 0; r < 4; ++r) {
        const int s = lb * 4 + r, e = we * 16 + lr;
        hw_off[r] = s * 128 + ((((e >> 3) ^ (s & 7)) << 4)) + (e & 7) * 2;
    }
    char* const sHb = reinterpret_cast<char*>(sH);
    char* const sHg = sHb + g2 * 8192;   // this group's loop region

    const float TL2 = 2.0f * L2E;   // 2*log2e

    #pragma unroll 2
    for (int step = 0; step < LL; ++step) {
        const int cb  = (step & 1) << 12;   // current buf base within group
        const int nb_ = cb ^ 4096;          // next buf base

        // 0. fused GCN gather (low prio): accumulate row `step`, issue row step+1
        if (step < 33) {
            gacc[0] += gld0.x; gacc[1] += gld0.y; gacc[2] += gld0.z; gacc[3] += gld0.w;
            gacc[4] += gld1.x; gacc[5] += gld1.y; gacc[6] += gld1.z; gacc[7] += gld1.w;
            if (step < 32) {
                const int gi = sNbr[gpair * 33 + step + 1];
                const float4* gp = reinterpret_cast<const float4*>(gut + (size_t)gi * EE);
                gld0 = gp[0]; gld1 = gp[1];
            }
        }

        // 1. issue x prefetch for step+2 (stays in flight across the barrier)
        short8 nxA0 = *reinterpret_cast<const short8*>(tbl8 + (size_t)idA * 128);
        short8 nxA1 = *reinterpret_cast<const short8*>(tbl8 + (size_t)idA * 128 + 64);
        short8 nxB0 = *reinterpret_cast<const short8*>(tbl8 + (size_t)idB * 128);
        short8 nxB1 = *reinterpret_cast<const short8*>(tbl8 + (size_t)idB * 128 + 64);
        {
            const int s2 = (step + 3 < LL) ? (step + 3) : (LL - 1);
            idA = sIdx[ibA + s2]; idB = sIdx[ibB + s2];
        }

        // ---- recurrence-critical section: prefer this wave on the CU ----
        __builtin_amdgcn_s_setprio(1);

        // 2. read h A-frags for both chains (swizzled, conflict-free)
        short8 ahA0 = *reinterpret_cast<const short8*>(sHg + cb + offA0);
        short8 ahA1 = *reinterpret_cast<const short8*>(sHg + cb + offA1);
        short8 ahB0 = *reinterpret_cast<const short8*>(sHg + cb + 2048 + offA0);
        short8 ahB1 = *reinterpret_cast<const short8*>(sHg + cb + 2048 + offA1);

        // 3. acc = xacc (bias + x-part, computed last step) + h @ sWhh^T
        v4f accA[4], accB[4];
        #pragma unroll
        for (int g = 0; g < 4; ++g) {
            v4f a = __builtin_amdgcn_mfma_f32_16x16x32_bf16(ahA0, Bf[1][g][0], xaccA[g], 0, 0, 0);
            accA[g] = __builtin_amdgcn_mfma_f32_16x16x32_bf16(ahA1, Bf[1][g][1], a, 0, 0, 0);
            v4f b = __builtin_amdgcn_mfma_f32_16x16x32_bf16(ahB0, Bf[1][g][0], xaccB[g], 0, 0, 0);
            accB[g] = __builtin_amdgcn_mfma_f32_16x16x32_bf16(ahB1, Bf[1][g][1], b, 0, 0, 0);
        }

        // 4. gate nonlinearities + h writes (pre-scaled c~; exp2 arg direct)
        {
            char* SH = sHg + nb_;
            #pragma unroll
            for (int r = 0; r < 4; ++r) {
                const float si = rcpf(1.0f + exp2_fast(accA[0][r]));
                const float sf = rcpf(1.0f + exp2_fast(accA[1][r]));
                const float tgs = fmaf(-2.0f * TL2, rcpf(1.0f + exp2_fast(accA[2][r])), TL2);
                const float so = rcpf(1.0f + exp2_fast(accA[3][r]));
                const float cc = fmaf(sf, cA[r], si * tgs);
                cA[r] = cc;
                hA[r] = so * fmaf(-2.0f, rcpf(1.0f + exp2_fast(cc)), 1.0f);
            }
            const unsigned a01 = cvt_pk_bf16(hA[0], hA[1]);
            const unsigned a23 = cvt_pk_bf16(hA[2], hA[3]);
            *reinterpret_cast<short*>(SH + hw_off[0]) = (short)(a01 & 0xFFFF);
            *reinterpret_cast<short*>(SH + hw_off[1]) = (short)(a01 >> 16);
            *reinterpret_cast<short*>(SH + hw_off[2]) = (short)(a23 & 0xFFFF);
            *reinterpret_cast<short*>(SH + hw_off[3]) = (short)(a23 >> 16);
            SH += 2048;
            #pragma unroll
            for (int r = 0; r < 4; ++r) {
                const float si = rcpf(1.0f + exp2_fast(accB[0][r]));
                const float sf = rcpf(1.0f + exp2_fast(accB[1][r]));
                const float tgs = fmaf(-2.0f * TL2, rcpf(1.0f + exp2_fast(accB[2][r])), TL2);
                const float so = rcpf(1.0f + exp2_fast(accB[3][r]));
                const float cc = fmaf(sf, cB[r], si * tgs);
                cB[r] = cc;
                hB[r] = so * fmaf(-2.0f, rcpf(1.0f + exp2_fast(cc)), 1.0f);
            }
            const unsigned b01 = cvt_pk_bf16(hB[0], hB[1]);
            const unsigned b23 = cvt_pk_bf16(hB[2], hB[3]);
            *reinterpret_cast<short*>(SH + hw_off[0]) = (short)(b01 & 0xFFFF);
            *reinterpret_cast<short*>(SH + hw_off[1]) = (short)(b01 >> 16);
            *reinterpret_cast<short*>(SH + hw_off[2]) = (short)(b23 & 0xFFFF);
            *reinterpret_cast<short*>(SH + hw_off[3]) = (short)(b23 >> 16);
        }

        __builtin_amdgcn_s_setprio(0);
        // ---- end critical section ----

        // 5. x-part of step+1's gates (off critical path; overlaps barrier wait)
        #pragma unroll
        for (int g = 0; g < 4; ++g) {
            v4f a; a[0] = bias[g]; a[1] = bias[g]; a[2] = bias[g]; a[3] = bias[g];
            a = __builtin_amdgcn_mfma_f32_16x16x32_bf16(pxA0, Bf[0][g][0], a, 0, 0, 0);
            xaccA[g] = __builtin_amdgcn_mfma_f32_16x16x32_bf16(pxA1, Bf[0][g][1], a, 0, 0, 0);
            v4f b; b[0] = bias[g]; b[1] = bias[g]; b[2] = bias[g]; b[3] = bias[g];
            b = __builtin_amdgcn_mfma_f32_16x16x32_bf16(pxB0, Bf[0][g][0], b, 0, 0, 0);
            xaccB[g] = __builtin_amdgcn_mfma_f32_16x16x32_bf16(pxB1, Bf[0][g][1], b, 0, 0, 0);
        }

        // 6. LDS-only barrier (x + gather loads stay in flight)
        block_sync_lds();

        // 7. roll prefetch regs
        pxA0 = nxA0; pxA1 = nxA1; pxB0 = nxB0; pxB1 = nxB1;
    }

    // ======================= FUSED POST EPILOGUE =======================
    // batches q=0..3 -> global b = blk*4 + q; local pair p = q*16 + m.

    // 1. stage agg/33 as bf16 into dead sH tiles 0..3 (same swizzle as h)
    {
        const float sc = 1.0f / 33.0f;
        uint4 pk;
        pk.x = cvt_pk_bf16(gacc[0] * sc, gacc[1] * sc);
        pk.y = cvt_pk_bf16(gacc[2] * sc, gacc[3] * sc);
        pk.z = cvt_pk_bf16(gacc[4] * sc, gacc[5] * sc);
        pk.w = cvt_pk_bf16(gacc[6] * sc, gacc[7] * sc);
        const int row = gpair & 15;
        const int off = ((gpair >> 4) << 11) + row * 128 + ((gec ^ (row & 7)) << 4);
        *reinterpret_cast<uint4*>(sHb + off) = pk;
    }
    __syncthreads();

    // 2. m_gcn = relu(agg @ gcn_W^T + b) via MFMA; fus = h + m_gcn.
    //    group g2 consumes tiles 2*g2 (chain A rows) and 2*g2+1 (chain B rows).
    {
        const char* base = sHb + g2 * 4096;
        short8 agA0 = *reinterpret_cast<const short8*>(base + offA0);
        short8 agA1 = *reinterpret_cast<const short8*>(base + offA1);
        short8 agB0 = *reinterpret_cast<const short8*>(base + 2048 + offA0);
        short8 agB1 = *reinterpret_cast<const short8*>(base + 2048 + offA1);
        v4f z4 = {0.0f, 0.0f, 0.0f, 0.0f};
        v4f gA = __builtin_amdgcn_mfma_f32_16x16x32_bf16(agA0, Bg[0], z4, 0, 0, 0);
        gA = __builtin_amdgcn_mfma_f32_16x16x32_bf16(agA1, Bg[1], gA, 0, 0, 0);
        v4f gB = __builtin_amdgcn_mfma_f32_16x16x32_bf16(agB0, Bg[0], z4, 0, 0, 0);
        gB = __builtin_amdgcn_mfma_f32_16x16x32_bf16(agB1, Bg[1], gB, 0, 0, 0);
        const int e = we * 16 + lr;
        #pragma unroll
        for (int r = 0; r < 4; ++r) {
            sFus[g2 * 32 + lb * 4 + r][e]      = hA[r] + fmaxf(gA[r] + gb, 0.0f);
            sFus[g2 * 32 + 16 + lb * 4 + r][e] = hB[r] + fmaxf(gB[r] + gb, 0.0f);
        }
    }
    __syncthreads();

    // 3. PNA reduce over M (amp = 1 exactly)
    if (t < 256) {
        const int q = t >> 6, e = t & 63;
        float mn = 0.0f, mx = -INFINITY;
        #pragma unroll
        for (int m = 0; m < MM; ++m) { float v = sFus[q * 16 + m][e]; mn += v; mx = fmaxf(mx, v); }
        mn *= (1.0f / 16.0f);
        sF[q][e] = mn; sF[q][64 + e] = mx; sF[q][128 + e] = mn; sF[q][192 + e] = mx;
    }
    __syncthreads();

    // 4. h1 = relu(feats @ pna_W1 + b1): 256->64; 4 batches x 2 k-halves x 64
    {
        const int q = t >> 7, kh = (t >> 6) & 1, j = t & 63;
        float p = 0.0f;
        const float* Wp = pna_W1 + (size_t)(kh * 128) * 64 + j;
        const float* fp = &sF[q][kh * 128];
        #pragma unroll 16
        for (int k = 0; k < 128; ++k) p = fmaf(fp[k], Wp[(size_t)k * 64], p);
        sP[q][kh][j] = p;
    }
    __syncthreads();
    if (t < 256) {
        const int q = t >> 6, j = t & 63;
        sH1[q][j] = fmaxf(pna_b1[j] + sP[q][0][j] + sP[q][1][j], 0.0f);
    }
    __syncthreads();

    // 5. h2 = relu(h1 @ pna_W2 + b2): k split 2x32
    {
        const int q = t >> 7, kh = (t >> 6) & 1, j = t & 63;
        float p = 0.0f;
        #pragma unroll
        for (int k = 0; k < 32; ++k)
            p = fmaf(sH1[q][kh * 32 + k], pna_W2[(size_t)(kh * 32 + k) * 64 + j], p);
        sP[q][kh][j] = p;
    }
    __syncthreads();
    if (t < 256) {
        const int q = t >> 6, j = t & 63;
        sH2[q][j] = fmaxf(pna_b2[j] + sP[q][0][j] + sP[q][1][j], 0.0f);
    }
    __syncthreads();

    // 6. grp = h2 @ pna_W3 + b3: k split 2x32
    {
        const int q = t >> 7, kh = (t >> 6) & 1, j = t & 63;
        float p = 0.0f;
        #pragma unroll
        for (int k = 0; k < 32; ++k)
            p = fmaf(sH2[q][kh * 32 + k], pna_W3[(size_t)(kh * 32 + k) * 64 + j], p);
        sP[q][kh][j] = p;
    }
    __syncthreads();
    if (t < 256) {
        const int q = t >> 6, j = t & 63;
        sGrp[q][j] = pna_b3[j] + sP[q][0][j] + sP[q][1][j];
    }
    __syncthreads();

    // 7. predict layer 1: 256 threads, k split 8x24; then 32-thread combine
    if (t < 256) {
        const int q = t >> 6, kg = (t >> 3) & 7, j = t & 7;
        float a = 0.0f;
        #pragma unroll
        for (int kk = 0; kk < 24; ++kk) {
            const int k = kg * 24 + kk;
            const float cv = (k < 64) ? sGrp[q][k] * sActe[q][k]
                                      : ((k < 128) ? sGrp[q][k - 64] : sActe[q][k - 128]);
            a = fmaf(cv, pred_W1[k * 8 + j], a);
        }
        sP7[q][kg][j] = a;
    }
    __syncthreads();
    if (t < 32) {
        const int q = t >> 3, j = t & 7;
        float a = pred_b1[j];
        #pragma unroll
        for (int kg = 0; kg < 8; ++kg) a += sP7[q][kg][j];
        sHH[q][j] = fmaxf(a, 0.0f);
    }
    __syncthreads();
    if (t < 4) {
        float y = pred_b2[0];
        #pragma unroll
        for (int jj = 0; jj < 8; ++jj) y = fmaf(sHH[t][jj], pred_W2[jj], y);
        out[blk * 4 + t] = 1.0f / (1.0f + expf(-y));
    }
}

extern "C" void kernel_launch(void* const* d_in, const int* in_sizes, int n_in,
                              void* d_out, int out_size, void* d_ws, size_t ws_size,
                              hipStream_t stream) {
    const int*   members    = (const int*)d_in[0];
    const int*   neighbors  = (const int*)d_in[1];
    const int*   act_inputs = (const int*)d_in[2];
    const int*   act_seqs   = (const int*)d_in[3];
    const float* act_table  = (const float*)d_in[4];
    const float* user_table = (const float*)d_in[5];
    const float* W_ih       = (const float*)d_in[6];
    const float* W_hh       = (const float*)d_in[7];
    const float* b_ih       = (const float*)d_in[8];
    const float* b_hh       = (const float*)d_in[9];
    const float* gcn_W      = (const float*)d_in[10];
    const float* gcn_b      = (const float*)d_in[11];
    const float* pna_W1     = (const float*)d_in[12];
    const float* pna_b1     = (const float*)d_in[13];
    const float* pna_W2     = (const float*)d_in[14];
    const float* pna_b2     = (const float*)d_in[15];
    const float* pna_W3     = (const float*)d_in[16];
    const float* pna_b3     = (const float*)d_in[17];
    const float* pred_W1    = (const float*)d_in[18];
    const float* pred_b1    = (const float*)d_in[19];
    const float* pred_W2    = (const float*)d_in[20];
    const float* pred_b2    = (const float*)d_in[21];

    unsigned short* act_bf = (unsigned short*)d_ws;   // 12.8 MB bf16 table

    cvt_table<<<dim3((NACT * EE / 8 + 255) / 256), dim3(256), 0, stream>>>(
        act_table, (unsigned*)act_bf);

    lstm_fused<<<dim3(256), dim3(512), 0, stream>>>(
        act_seqs, act_bf, members, neighbors, user_table,
        W_ih, W_hh, b_ih, b_hh,
        act_inputs, act_table,
        gcn_W, gcn_b, pna_W1, pna_b1, pna_W2, pna_b2, pna_W3, pna_b3,
        pred_W1, pred_b1, pred_W2, pred_b2, (float*)d_out);
}

// Round 20
// 103.454 us; speedup vs baseline: 5.2998x; 1.1035x over previous
//
#include <hip/hip_runtime.h>
#include <hip/hip_bf16.h>
#include <math.h>

// Problem constants (match reference)
#define BB   1024
#define MM   16
#define KK   32
#define LL   50
#define EE   64
#define NACT 100000

typedef __attribute__((ext_vector_type(8))) short short8;
typedef float v4f __attribute__((ext_vector_type(4)));

__device__ __forceinline__ float rcpf(float x) { return __builtin_amdgcn_rcpf(x); }
// native 2^x (v_exp_f32 IS exp2)
__device__ __forceinline__ float exp2_fast(float x) {
    float r;
    asm("v_exp_f32 %0, %1" : "=v"(r) : "v"(x));
    return r;
}

// packed f32x2 -> bf16x2 (lo->low16, hi->high16), RNE
__device__ __forceinline__ unsigned cvt_pk_bf16(float lo, float hi) {
    unsigned r;
    asm("v_cvt_pk_bf16_f32 %0, %1, %2" : "=v"(r) : "v"(lo), "v"(hi));
    return r;
}

// Block-wide barrier that does NOT drain vmcnt: LDS writes are made visible
// (lgkmcnt(0)) but global prefetch loads stay in flight across the barrier.
__device__ __forceinline__ void block_sync_lds() {
    __builtin_amdgcn_sched_barrier(0);
    asm volatile("s_waitcnt lgkmcnt(0)" ::: "memory");
    __builtin_amdgcn_s_barrier();
    __builtin_amdgcn_sched_barrier(0);
}

// ---------------------------------------------------------------------------
// Pre-pass: act_table f32 -> bf16 (row-major, same layout). 8 floats/thread.
// ---------------------------------------------------------------------------
__global__ __launch_bounds__(256)
void cvt_table(const float* __restrict__ src, unsigned* __restrict__ dst)
{
    const int i = blockIdx.x * 256 + threadIdx.x;          // unit = 8 floats
    if (i < (NACT * EE) / 8) {
        const float4* s = reinterpret_cast<const float4*>(src) + (size_t)i * 2;
        float4 a = s[0], b = s[1];
        uint4 o;
        o.x = cvt_pk_bf16(a.x, a.y);
        o.y = cvt_pk_bf16(a.z, a.w);
        o.z = cvt_pk_bf16(b.x, b.y);
        o.w = cvt_pk_bf16(b.z, b.w);
        reinterpret_cast<uint4*>(dst)[i] = o;
    }
}

// ---------------------------------------------------------------------------
// FULLY-FUSED kernel (r17 == best measured 103.4 us, terminal revert).
// Structure: dual-chain LSTM (512 blocks x 256 thr, 32 seqs/block, 2 blk/CU),
// exp2-folded gates (weights/biases pre-scaled so MFMA output feeds
// v_exp_f32 directly), pre-scaled cell state, fused GCN gather riding the
// LSTM's idle HBM, cross-step x-GEMM pipelining, setprio around the
// recurrence-critical section, MFMA epilogue for the GCN linear, and the
// full PNA+MLP+predict chain fused in-block (4 batches... 2 per block).
// Occupancy quadrants measured and closed: r8 (1-wave barrier-free) -40%,
// r9 (3 blk/CU single-chain) -7%, r18 ((512,4) cap) spill 5x, r19
// ((512,2) 8-wave) -10% (second block never resident). This kernel is
// recurrence-latency bound: ~350-400 cyc irreducible serial chain per step.
// ---------------------------------------------------------------------------
__global__ __launch_bounds__(256, 2)
void lstm_fused(const int* __restrict__ act_seqs, const unsigned short* __restrict__ act_bf,
                const int* __restrict__ members, const int* __restrict__ neighbors,
                const float* __restrict__ user_table,
                const float* __restrict__ W_ih, const float* __restrict__ W_hh,
                const float* __restrict__ b_ih, const float* __restrict__ b_hh,
                const int* __restrict__ act_inputs, const float* __restrict__ act_table,
                const float* __restrict__ gcn_W, const float* __restrict__ gcn_b,
                const float* __restrict__ pna_W1, const float* __restrict__ pna_b1,
                const float* __restrict__ pna_W2, const float* __restrict__ pna_b2,
                const float* __restrict__ pna_W3, const float* __restrict__ pna_b3,
                const float* __restrict__ pred_W1, const float* __restrict__ pred_b1,
                const float* __restrict__ pred_W2, const float* __restrict__ pred_b2,
                float* __restrict__ out)
{
    // --- loop-phase LDS
    __shared__ __align__(16) short sH[4][1024];   // h dbuf (bf16 swizzled), 8 KB
    __shared__ int sIdx[32 * LL];                 // 6.4 KB
    __shared__ int sNbr[32 * 33];                 // 4.2 KB
    // --- epilogue LDS
    __shared__ float sFus[32][66];                // padded: conflict-free col reads
    __shared__ float sF[2][256];                  // PNA feats
    __shared__ float sP[2][2][64];                // k-split partials
    __shared__ float sP7[2][8][8];                // predict partials
    __shared__ float sH1[2][64];
    __shared__ float sH2[2][64];
    __shared__ float sGrp[2][64];
    __shared__ float sActe[2][64];
    __shared__ float sHH[2][8];

    const int t    = threadIdx.x;
    const int blk  = blockIdx.x;
    const int lane = t & 63;
    const int w    = t >> 6;        // wave id = e-block (0..3)
    const int lr   = lane & 15;     // A row (seq) / B,D col selector
    const int lb   = lane >> 4;     // k-block / D row-block selector

    // --- this block's indices (contiguous 1600 ints, coalesced)
    for (int i = t; i < 32 * LL; i += 256) sIdx[i] = act_seqs[blk * (32 * LL) + i];
    // --- gather row ids: pair p (= global b*16+m = blk*32+p), j=0 member, 1..32 nbrs
    for (int i = t; i < 32 * 33; i += 256) {
        const int p = i / 33, j = i - p * 33;
        const int base = blk * 32 + p;
        sNbr[i] = (j == 0) ? members[base] : neighbors[base * KK + j - 1];
    }
    // --- stage act_e for both batches (prologue: latency hidden under setup)
    if (t < 128) {
        const int q = t >> 6, e = t & 63;
        sActe[q][e] = act_table[(size_t)act_inputs[blk * 2 + q] * EE + e];
    }

    // per-gate exp2 fold scales (i,f,o: -log2e; g: +2*log2e)
    const float L2E = 1.44269504088896f;
    float gscale[4];
    gscale[0] = -L2E; gscale[1] = -L2E; gscale[2] = 2.0f * L2E; gscale[3] = -L2E;

    // --- weights -> register B-frags, SCALED. gates = in @ W^T => B[k][j]=W[j][k].
    short8 Bf[2][4][2];   // [mat(ih,hh)][gate][ks]
    #pragma unroll
    for (int mat = 0; mat < 2; ++mat) {
        const float* W = mat ? W_hh : W_ih;
        #pragma unroll
        for (int g = 0; g < 4; ++g) {
            const int j = g * 64 + w * 16 + lr;
            const float sc = gscale[g];
            #pragma unroll
            for (int ks = 0; ks < 2; ++ks) {
                const float4* p = reinterpret_cast<const float4*>(&W[(size_t)j * 64 + ks * 32 + lb * 8]);
                float4 v0 = p[0], v1 = p[1];
                uint4 o;
                o.x = cvt_pk_bf16(sc * v0.x, sc * v0.y);
                o.y = cvt_pk_bf16(sc * v0.z, sc * v0.w);
                o.z = cvt_pk_bf16(sc * v1.x, sc * v1.y);
                o.w = cvt_pk_bf16(sc * v1.z, sc * v1.w);
                Bf[mat][g][ks] = __builtin_bit_cast(short8, o);
            }
        }
    }
    // --- gcn_W -> register B-frags (epilogue MFMA), unscaled bf16 RNE
    short8 Bg[2];
    #pragma unroll
    for (int ks = 0; ks < 2; ++ks) {
        const int j = w * 16 + lr;
        const float4* p = reinterpret_cast<const float4*>(&gcn_W[(size_t)j * 64 + ks * 32 + lb * 8]);
        float4 v0 = p[0], v1 = p[1];
        uint4 o;
        o.x = cvt_pk_bf16(v0.x, v0.y);
        o.y = cvt_pk_bf16(v0.z, v0.w);
        o.z = cvt_pk_bf16(v1.x, v1.y);
        o.w = cvt_pk_bf16(v1.z, v1.w);
        Bg[ks] = __builtin_bit_cast(short8, o);
    }
    const float gb = gcn_b[w * 16 + lr];

    float bias[4];
    #pragma unroll
    for (int g = 0; g < 4; ++g) {
        const int j = g * 64 + w * 16 + lr;
        bias[g] = gscale[g] * (b_ih[j] + b_hh[j]);
    }

    // cell state kept pre-scaled: c~ = 2*L2E*c (so exp2 arg is c~ directly)
    float hA[4], cA[4], hB[4], cB[4];
    #pragma unroll
    for (int r = 0; r < 4; ++r) { hA[r] = 0.0f; cA[r] = 0.0f; hB[r] = 0.0f; cB[r] = 0.0f; }

    // zero buf0 (tiles 0,1 = 4096 B = 256 x uint4)
    reinterpret_cast<uint4*>(sH)[t] = make_uint4(0u, 0u, 0u, 0u);
    __syncthreads();   // sIdx + sNbr + sActe + sH buf0 visible (once)

    // --- gather lane mapping: pair p = t>>3 owns row blk*32+p; chunk ec = t&7
    const int gpair = t >> 3;
    const int gec   = t & 7;
    const float* gut = user_table + (size_t)gec * 8;
    float gacc[8];
    #pragma unroll
    for (int q = 0; q < 8; ++q) gacc[q] = 0.0f;
    // pre-issue gather row 0 (BEFORE x pre-loads: older in vmcnt FIFO)
    float4 gld0, gld1;
    {
        const int gi = sNbr[gpair * 33 + 0];
        const float4* gp = reinterpret_cast<const float4*>(gut + (size_t)gi * EE);
        gld0 = gp[0]; gld1 = gp[1];
    }

    // --- x gather: lane's frag = bytes [id*128 + lb*16] and +64.
    const char* tbl8 = reinterpret_cast<const char*>(act_bf) + lb * 16;
    const int ibA = lr * LL;           // chain A: seq lr
    const int ibB = (16 + lr) * LL;    // chain B: seq 16+lr

    // prologue: load x_0, compute xacc for step 0; load x_1 -> px; idx -> x_2
    int idA = sIdx[ibA + 0], idB = sIdx[ibB + 0];
    short8 c0A0 = *reinterpret_cast<const short8*>(tbl8 + (size_t)idA * 128);
    short8 c0A1 = *reinterpret_cast<const short8*>(tbl8 + (size_t)idA * 128 + 64);
    short8 c0B0 = *reinterpret_cast<const short8*>(tbl8 + (size_t)idB * 128);
    short8 c0B1 = *reinterpret_cast<const short8*>(tbl8 + (size_t)idB * 128 + 64);
    idA = sIdx[ibA + 1]; idB = sIdx[ibB + 1];
    short8 pxA0 = *reinterpret_cast<const short8*>(tbl8 + (size_t)idA * 128);
    short8 pxA1 = *reinterpret_cast<const short8*>(tbl8 + (size_t)idA * 128 + 64);
    short8 pxB0 = *reinterpret_cast<const short8*>(tbl8 + (size_t)idB * 128);
    short8 pxB1 = *reinterpret_cast<const short8*>(tbl8 + (size_t)idB * 128 + 64);
    idA = sIdx[ibA + 2]; idB = sIdx[ibB + 2];

    v4f xaccA[4], xaccB[4];
    #pragma unroll
    for (int g = 0; g < 4; ++g) {
        v4f a; a[0] = bias[g]; a[1] = bias[g]; a[2] = bias[g]; a[3] = bias[g];
        a = __builtin_amdgcn_mfma_f32_16x16x32_bf16(c0A0, Bf[0][g][0], a, 0, 0, 0);
        xaccA[g] = __builtin_amdgcn_mfma_f32_16x16x32_bf16(c0A1, Bf[0][g][1], a, 0, 0, 0);
        v4f b; b[0] = bias[g]; b[1] = bias[g]; b[2] = bias[g]; b[3] = bias[g];
        b = __builtin_amdgcn_mfma_f32_16x16x32_bf16(c0B0, Bf[0][g][0], b, 0, 0, 0);
        xaccB[g] = __builtin_amdgcn_mfma_f32_16x16x32_bf16(c0B1, Bf[0][g][1], b, 0, 0, 0);
    }

    // LDS byte offsets (loop-invariant)
    const int offA0 = lr * 128 + ((lb ^ (lr & 7)) << 4);
    const int offA1 = lr * 128 + (((lb + 4) ^ (lr & 7)) << 4);
    int hw_off[4];
    #pragma unroll
    for (int r = 0; r < 4; ++r) {
        const int s = lb * 4 + r, e = w * 16 + lr;
        hw_off[r] = s * 128 + ((((e >> 3) ^ (s & 7)) << 4)) + (e & 7) * 2;
    }
    char* const sHb = reinterpret_cast<char*>(sH);

    const float TL2 = 2.0f * L2E;   // 2*log2e

    #pragma unroll 2
    for (int step = 0; step < LL; ++step) {
        const int cb  = (step & 1) << 12;   // current buf base: 0 or 4096
        const int nb_ = cb ^ 4096;          // next buf base

        // 0. fused GCN gather (low prio): accumulate row `step`, issue row step+1
        if (step < 33) {
            gacc[0] += gld0.x; gacc[1] += gld0.y; gacc[2] += gld0.z; gacc[3] += gld0.w;
            gacc[4] += gld1.x; gacc[5] += gld1.y; gacc[6] += gld1.z; gacc[7] += gld1.w;
            if (step < 32) {
                const int gi = sNbr[gpair * 33 + step + 1];
                const float4* gp = reinterpret_cast<const float4*>(gut + (size_t)gi * EE);
                gld0 = gp[0]; gld1 = gp[1];
            }
        }

        // 1. issue x prefetch for step+2 (stays in flight across the barrier)
        short8 nxA0 = *reinterpret_cast<const short8*>(tbl8 + (size_t)idA * 128);
        short8 nxA1 = *reinterpret_cast<const short8*>(tbl8 + (size_t)idA * 128 + 64);
        short8 nxB0 = *reinterpret_cast<const short8*>(tbl8 + (size_t)idB * 128);
        short8 nxB1 = *reinterpret_cast<const short8*>(tbl8 + (size_t)idB * 128 + 64);
        {
            const int s2 = (step + 3 < LL) ? (step + 3) : (LL - 1);
            idA = sIdx[ibA + s2]; idB = sIdx[ibB + s2];
        }

        // ---- recurrence-critical section: prefer this wave on the CU ----
        __builtin_amdgcn_s_setprio(1);

        // 2. read h A-frags for both chains (swizzled, conflict-free)
        short8 ahA0 = *reinterpret_cast<const short8*>(sHb + cb + offA0);
        short8 ahA1 = *reinterpret_cast<const short8*>(sHb + cb + offA1);
        short8 ahB0 = *reinterpret_cast<const short8*>(sHb + cb + 2048 + offA0);
        short8 ahB1 = *reinterpret_cast<const short8*>(sHb + cb + 2048 + offA1);

        // 3. acc = xacc (bias + x-part, computed last step) + h @ sWhh^T
        v4f accA[4], accB[4];
        #pragma unroll
        for (int g = 0; g < 4; ++g) {
            v4f a = __builtin_amdgcn_mfma_f32_16x16x32_bf16(ahA0, Bf[1][g][0], xaccA[g], 0, 0, 0);
            accA[g] = __builtin_amdgcn_mfma_f32_16x16x32_bf16(ahA1, Bf[1][g][1], a, 0, 0, 0);
            v4f b = __builtin_amdgcn_mfma_f32_16x16x32_bf16(ahB0, Bf[1][g][0], xaccB[g], 0, 0, 0);
            accB[g] = __builtin_amdgcn_mfma_f32_16x16x32_bf16(ahB1, Bf[1][g][1], b, 0, 0, 0);
        }

        // 4. gate nonlinearities + h writes. c kept pre-scaled (c~ = 2L2E*c):
        //    tgs = 2L2E*tanh(g) = fmaf(-2*TL2, rcp, TL2); exp2 arg is c~ directly.
        {
            char* SH = sHb + nb_;
            #pragma unroll
            for (int r = 0; r < 4; ++r) {
                const float si = rcpf(1.0f + exp2_fast(accA[0][r]));
                const float sf = rcpf(1.0f + exp2_fast(accA[1][r]));
                const float tgs = fmaf(-2.0f * TL2, rcpf(1.0f + exp2_fast(accA[2][r])), TL2);
                const float so = rcpf(1.0f + exp2_fast(accA[3][r]));
                const float cc = fmaf(sf, cA[r], si * tgs);   // pre-scaled cell
                cA[r] = cc;
                hA[r] = so * fmaf(-2.0f, rcpf(1.0f + exp2_fast(cc)), 1.0f);
            }
            const unsigned a01 = cvt_pk_bf16(hA[0], hA[1]);
            const unsigned a23 = cvt_pk_bf16(hA[2], hA[3]);
            *reinterpret_cast<short*>(SH + hw_off[0]) = (short)(a01 & 0xFFFF);
            *reinterpret_cast<short*>(SH + hw_off[1]) = (short)(a01 >> 16);
            *reinterpret_cast<short*>(SH + hw_off[2]) = (short)(a23 & 0xFFFF);
            *reinterpret_cast<short*>(SH + hw_off[3]) = (short)(a23 >> 16);
            SH += 2048;
            #pragma unroll
            for (int r = 0; r < 4; ++r) {
                const float si = rcpf(1.0f + exp2_fast(accB[0][r]));
                const float sf = rcpf(1.0f + exp2_fast(accB[1][r]));
                const float tgs = fmaf(-2.0f * TL2, rcpf(1.0f + exp2_fast(accB[2][r])), TL2);
                const float so = rcpf(1.0f + exp2_fast(accB[3][r]));
                const float cc = fmaf(sf, cB[r], si * tgs);
                cB[r] = cc;
                hB[r] = so * fmaf(-2.0f, rcpf(1.0f + exp2_fast(cc)), 1.0f);
            }
            const unsigned b01 = cvt_pk_bf16(hB[0], hB[1]);
            const unsigned b23 = cvt_pk_bf16(hB[2], hB[3]);
            *reinterpret_cast<short*>(SH + hw_off[0]) = (short)(b01 & 0xFFFF);
            *reinterpret_cast<short*>(SH + hw_off[1]) = (short)(b01 >> 16);
            *reinterpret_cast<short*>(SH + hw_off[2]) = (short)(b23 & 0xFFFF);
            *reinterpret_cast<short*>(SH + hw_off[3]) = (short)(b23 >> 16);
        }

        __builtin_amdgcn_s_setprio(0);
        // ---- end critical section ----

        // 5. x-part of step+1's gates (off critical path; overlaps barrier wait)
        #pragma unroll
        for (int g = 0; g < 4; ++g) {
            v4f a; a[0] = bias[g]; a[1] = bias[g]; a[2] = bias[g]; a[3] = bias[g];
            a = __builtin_amdgcn_mfma_f32_16x16x32_bf16(pxA0, Bf[0][g][0], a, 0, 0, 0);
            xaccA[g] = __builtin_amdgcn_mfma_f32_16x16x32_bf16(pxA1, Bf[0][g][1], a, 0, 0, 0);
            v4f b; b[0] = bias[g]; b[1] = bias[g]; b[2] = bias[g]; b[3] = bias[g];
            b = __builtin_amdgcn_mfma_f32_16x16x32_bf16(pxB0, Bf[0][g][0], b, 0, 0, 0);
            xaccB[g] = __builtin_amdgcn_mfma_f32_16x16x32_bf16(pxB1, Bf[0][g][1], b, 0, 0, 0);
        }

        // 6. LDS-only barrier (x + gather loads stay in flight)
        block_sync_lds();

        // 7. roll prefetch regs (unroll-2 lets the allocator rename these)
        pxA0 = nxA0; pxA1 = nxA1; pxB0 = nxB0; pxB1 = nxB1;
    }

    // ======================= FUSED POST EPILOGUE =======================
    // batches q=0,1 -> global b = blk*2 + q; local pair p = q*16 + m.

    // 1. stage agg/33 as bf16 into dead sH tiles 0,1 (same swizzle as h)
    {
        const float sc = 1.0f / 33.0f;
        uint4 pk;
        pk.x = cvt_pk_bf16(gacc[0] * sc, gacc[1] * sc);
        pk.y = cvt_pk_bf16(gacc[2] * sc, gacc[3] * sc);
        pk.z = cvt_pk_bf16(gacc[4] * sc, gacc[5] * sc);
        pk.w = cvt_pk_bf16(gacc[6] * sc, gacc[7] * sc);
        const int row = gpair & 15;
        const int off = ((gpair >> 4) << 11) + row * 128 + ((gec ^ (row & 7)) << 4);
        *reinterpret_cast<uint4*>(sHb + off) = pk;
    }
    __syncthreads();

    // 2. m_gcn = relu(agg @ gcn_W^T + b) via MFMA; fus = h + m_gcn.
    {
        short8 agA0 = *reinterpret_cast<const short8*>(sHb + offA0);
        short8 agA1 = *reinterpret_cast<const short8*>(sHb + offA1);
        short8 agB0 = *reinterpret_cast<const short8*>(sHb + 2048 + offA0);
        short8 agB1 = *reinterpret_cast<const short8*>(sHb + 2048 + offA1);
        v4f z4 = {0.0f, 0.0f, 0.0f, 0.0f};
        v4f gA = __builtin_amdgcn_mfma_f32_16x16x32_bf16(agA0, Bg[0], z4, 0, 0, 0);
        gA = __builtin_amdgcn_mfma_f32_16x16x32_bf16(agA1, Bg[1], gA, 0, 0, 0);
        v4f gB = __builtin_amdgcn_mfma_f32_16x16x32_bf16(agB0, Bg[0], z4, 0, 0, 0);
        gB = __builtin_amdgcn_mfma_f32_16x16x32_bf16(agB1, Bg[1], gB, 0, 0, 0);
        const int e = w * 16 + lr;
        #pragma unroll
        for (int r = 0; r < 4; ++r) {
            sFus[lb * 4 + r][e]      = hA[r] + fmaxf(gA[r] + gb, 0.0f);
            sFus[16 + lb * 4 + r][e] = hB[r] + fmaxf(gB[r] + gb, 0.0f);
        }
    }
    __syncthreads();

    // 3. PNA reduce over M (amp = 1 exactly)
    if (t < 128) {
        const int q = t >> 6, e = t & 63;
        float mn = 0.0f, mx = -INFINITY;
        #pragma unroll
        for (int m = 0; m < MM; ++m) { float v = sFus[q * 16 + m][e]; mn += v; mx = fmaxf(mx, v); }
        mn *= (1.0f / 16.0f);
        sF[q][e] = mn; sF[q][64 + e] = mx; sF[q][128 + e] = mn; sF[q][192 + e] = mx;
    }
    __syncthreads();

    // 4. h1 = relu(feats @ pna_W1 + b1): 256->64, k split 2x128 over 256 thr
    {
        const int q = t >> 7, kh = (t >> 6) & 1, j = t & 63;
        float p = 0.0f;
        const float* Wp = pna_W1 + (size_t)(kh * 128) * 64 + j;
        const float* fp = &sF[q][kh * 128];
        #pragma unroll 16
        for (int k = 0; k < 128; ++k) p = fmaf(fp[k], Wp[(size_t)k * 64], p);
        sP[q][kh][j] = p;
    }
    __syncthreads();
    if (t < 128) {
        const int q = t >> 6, j = t & 63;
        sH1[q][j] = fmaxf(pna_b1[j] + sP[q][0][j] + sP[q][1][j], 0.0f);
    }
    __syncthreads();

    // 5. h2 = relu(h1 @ pna_W2 + b2): k split 2x32 over 256 thr
    {
        const int q = t >> 7, kh = (t >> 6) & 1, j = t & 63;
        float p = 0.0f;
        #pragma unroll
        for (int k = 0; k < 32; ++k)
            p = fmaf(sH1[q][kh * 32 + k], pna_W2[(size_t)(kh * 32 + k) * 64 + j], p);
        sP[q][kh][j] = p;
    }
    __syncthreads();
    if (t < 128) {
        const int q = t >> 6, j = t & 63;
        sH2[q][j] = fmaxf(pna_b2[j] + sP[q][0][j] + sP[q][1][j], 0.0f);
    }
    __syncthreads();

    // 6. grp = h2 @ pna_W3 + b3: k split 2x32 over 256 thr
    {
        const int q = t >> 7, kh = (t >> 6) & 1, j = t & 63;
        float p = 0.0f;
        #pragma unroll
        for (int k = 0; k < 32; ++k)
            p = fmaf(sH2[q][kh * 32 + k], pna_W3[(size_t)(kh * 32 + k) * 64 + j], p);
        sP[q][kh][j] = p;
    }
    __syncthreads();
    if (t < 128) {
        const int q = t >> 6, j = t & 63;
        sGrp[q][j] = pna_b3[j] + sP[q][0][j] + sP[q][1][j];
    }
    __syncthreads();

    // 7. predict layer 1: 128 threads, k split 8x24; then 16-thread combine
    if (t < 128) {
        const int q = t >> 6, kg = (t >> 3) & 7, j = t & 7;
        float a = 0.0f;
        #pragma unroll
        for (int kk = 0; kk < 24; ++kk) {
            const int k = kg * 24 + kk;
            const float cv = (k < 64) ? sGrp[q][k] * sActe[q][k]
                                      : ((k < 128) ? sGrp[q][k - 64] : sActe[q][k - 128]);
            a = fmaf(cv, pred_W1[k * 8 + j], a);
        }
        sP7[q][kg][j] = a;
    }
    __syncthreads();
    if (t < 16) {
        const int q = t >> 3, j = t & 7;
        float a = pred_b1[j];
        #pragma unroll
        for (int kg = 0; kg < 8; ++kg) a += sP7[q][kg][j];
        sHH[q][j] = fmaxf(a, 0.0f);
    }
    __syncthreads();
    if (t < 2) {
        float y = pred_b2[0];
        #pragma unroll
        for (int jj = 0; jj < 8; ++jj) y = fmaf(sHH[t][jj], pred_W2[jj], y);
        out[blk * 2 + t] = 1.0f / (1.0f + expf(-y));
    }
}

extern "C" void kernel_launch(void* const* d_in, const int* in_sizes, int n_in,
                              void* d_out, int out_size, void* d_ws, size_t ws_size,
                              hipStream_t stream) {
    const int*   members    = (const int*)d_in[0];
    const int*   neighbors  = (const int*)d_in[1];
    const int*   act_inputs = (const int*)d_in[2];
    const int*   act_seqs   = (const int*)d_in[3];
    const float* act_table  = (const float*)d_in[4];
    const float* user_table = (const float*)d_in[5];
    const float* W_ih       = (const float*)d_in[6];
    const float* W_hh       = (const float*)d_in[7];
    const float* b_ih       = (const float*)d_in[8];
    const float* b_hh       = (const float*)d_in[9];
    const float* gcn_W      = (const float*)d_in[10];
    const float* gcn_b      = (const float*)d_in[11];
    const float* pna_W1     = (const float*)d_in[12];
    const float* pna_b1     = (const float*)d_in[13];
    const float* pna_W2     = (const float*)d_in[14];
    const float* pna_b2     = (const float*)d_in[15];
    const float* pna_W3     = (const float*)d_in[16];
    const float* pna_b3     = (const float*)d_in[17];
    const float* pred_W1    = (const float*)d_in[18];
    const float* pred_b1    = (const float*)d_in[19];
    const float* pred_W2    = (const float*)d_in[20];
    const float* pred_b2    = (const float*)d_in[21];

    unsigned short* act_bf = (unsigned short*)d_ws;   // 12.8 MB bf16 table

    cvt_table<<<dim3((NACT * EE / 8 + 255) / 256), dim3(256), 0, stream>>>(
        act_table, (unsigned*)act_bf);

    lstm_fused<<<dim3(512), dim3(256), 0, stream>>>(
        act_seqs, act_bf, members, neighbors, user_table,
        W_ih, W_hh, b_ih, b_hh,
        act_inputs, act_table,
        gcn_W, gcn_b, pna_W1, pna_b1, pna_W2, pna_b2, pna_W3, pna_b3,
        pred_W1, pred_b1, pred_W2, pred_b2, (float*)d_out);
}